// Round 1
// baseline (147.359 us; speedup 1.0000x reference)
//
#include <hip/hip_runtime.h>
#include <math.h>

#define TSAMP 30
#define FEPS 1e-15f

// picked log-prob for a 2-class row: l_y - logsumexp(a, b)
__device__ __forceinline__ float picked_lp(float a, float b, int y) {
    float m  = fmaxf(a, b);
    float mn = fminf(a, b);
    float lse = m + __logf(1.0f + __expf(mn - m));
    return (y ? b : a) - lse;
}

// Kernel 1: per-block partial sums of the 32 accumulators:
//   acc[0..29] = sum_i picked(distorted_t)   (t = 0..29)
//   acc[30]    = sum_i picked(undistorted)
//   acc[31]    = sum_i (exp(var_i) - 1)
// Each thread handles 2 consecutive rows -> float4 loads everywhere.
__global__ __launch_bounds__(256) void bcc_partial(
    const float4* __restrict__ logit4,   // [npair]  (2 rows x 2 classes)
    const float2* __restrict__ var2,     // [npair]
    const int2*   __restrict__ true2,    // [npair]
    const float4* __restrict__ noise4,   // [TSAMP][npair]
    float* __restrict__ partial,         // [32][nblk]
    int npair, int nblk)
{
    float acc[TSAMP];
    #pragma unroll
    for (int t = 0; t < TSAMP; ++t) acc[t] = 0.0f;
    float u_acc = 0.0f, vd_acc = 0.0f;

    const int stride = gridDim.x * blockDim.x;
    for (int p = blockIdx.x * blockDim.x + threadIdx.x; p < npair; p += stride) {
        const float4 lg = logit4[p];
        const float2 v  = var2[p];
        const int2   yy = true2[p];

        const float l00 = lg.x + FEPS, l01 = lg.y + FEPS;
        const float l10 = lg.z + FEPS, l11 = lg.w + FEPS;
        const float std0 = __fsqrt_rn(v.x) + FEPS;
        const float std1 = __fsqrt_rn(v.y) + FEPS;

        vd_acc += (__expf(v.x) - 1.0f) + (__expf(v.y) - 1.0f);
        u_acc  += picked_lp(l00, l01, yy.x) + picked_lp(l10, l11, yy.y);

        const float4* nptr = noise4 + p;
        #pragma unroll
        for (int t = 0; t < TSAMP; ++t) {
            const float4 nz = nptr[(size_t)t * (size_t)npair];
            const float d00 = fmaf(std0, nz.x, l00);
            const float d01 = fmaf(std0, nz.y, l01);
            const float d10 = fmaf(std1, nz.z, l10);
            const float d11 = fmaf(std1, nz.w, l11);
            acc[t] += picked_lp(d00, d01, yy.x) + picked_lp(d10, d11, yy.y);
        }
    }

    // block reduction of the 32 accumulators (deterministic, no atomics)
    __shared__ float s_part[4][32];
    const int lane = threadIdx.x & 63;
    const int wav  = threadIdx.x >> 6;
    #pragma unroll
    for (int a = 0; a < 32; ++a) {
        float vv = (a < TSAMP) ? acc[a] : ((a == TSAMP) ? u_acc : vd_acc);
        #pragma unroll
        for (int off = 32; off >= 1; off >>= 1)
            vv += __shfl_down(vv, off, 64);
        if (lane == 0) s_part[wav][a] = vv;
    }
    __syncthreads();
    if (threadIdx.x < 32) {
        const int a = threadIdx.x;
        const float s = s_part[0][a] + s_part[1][a] + s_part[2][a] + s_part[3][a];
        partial[(size_t)a * (size_t)nblk + blockIdx.x] = s;
    }
}

// Kernel 2: reduce partials per accumulator (fixed order) + scalar epilogue.
__global__ __launch_bounds__(256) void bcc_final(
    const float* __restrict__ partial,   // [32][nblk]
    int nblk, float invN, float* __restrict__ out)
{
    __shared__ float res[32];
    const int lane = threadIdx.x & 63;
    const int wav  = threadIdx.x >> 6;   // 0..3
    for (int a = wav; a < 32; a += 4) {
        float s = 0.0f;
        for (int j = lane; j < nblk; j += 64)
            s += partial[(size_t)a * (size_t)nblk + j];
        #pragma unroll
        for (int off = 32; off >= 1; off >>= 1)
            s += __shfl_down(s, off, 64);
        if (lane == 0) res[a] = s;
    }
    __syncthreads();
    if (threadIdx.x == 0) {
        const float U  = -res[30] * invN;           // undistorted_loss
        const float vd =  res[31] * invN;           // mean variance_depressor
        float mc_sum = 0.0f;
        #pragma unroll
        for (int t = 0; t < TSAMP; ++t) {
            const float D = -res[t] * invN;         // distorted_loss[t]
            const float x = U - D;
            const float e = (x > 0.0f) ? x : expm1f(x);   // elu(x)
            mc_sum += -e;                            // monte_carlo[t]
        }
        const float variance_loss = (mc_sum / (float)TSAMP) * U;
        out[0] = variance_loss + U + vd;
    }
}

extern "C" void kernel_launch(void* const* d_in, const int* in_sizes, int n_in,
                              void* d_out, int out_size, void* d_ws, size_t ws_size,
                              hipStream_t stream) {
    const float* logit = (const float*)d_in[0];   // [N,2] f32
    const float* var   = (const float*)d_in[1];   // [N,1] f32
    const int*   tru   = (const int*)d_in[2];     // [N]   i32
    const float* noise = (const float*)d_in[3];   // [30,N,2] f32
    float* out = (float*)d_out;

    const int N = in_sizes[1];          // var has N elements
    const int npair = N / 2;

    int nblk = 2048;
    const size_t need = (size_t)32 * (size_t)nblk * sizeof(float);
    if (ws_size < need) {
        nblk = (int)(ws_size / (32 * sizeof(float)));
        if (nblk < 1) nblk = 1;
    }
    float* partial = (float*)d_ws;

    bcc_partial<<<nblk, 256, 0, stream>>>(
        (const float4*)logit, (const float2*)var, (const int2*)tru,
        (const float4*)noise, partial, npair, nblk);

    bcc_final<<<1, 256, 0, stream>>>(partial, nblk, 1.0f / (float)N, out);
}

// Round 2
// 68.379 us; speedup vs baseline: 2.1550x; 2.1550x over previous
//
#include <hip/hip_runtime.h>
#include <math.h>

#define TSAMP 30
#define FEPS 1e-15f

// stable softplus: log1p(exp(x))
__device__ __forceinline__ float softplus(float x) {
    float m = fmaxf(x, 0.0f);
    return m + __logf(__expf(x - m) + __expf(-m));
}

// Kernel 1: per-block partial sums of 32 accumulators.
//   acc[0..29] = sum_i picked(distorted_t)  = sum_i -softplus(delta_i + ss_i*(n0-n1))
//   acc[30]    = sum_i picked(undistorted)  = sum_i -softplus(delta_i)
//   acc[31]    = sum_i (exp(var_i) - 1)
// where delta = sigma*(a-b), ss = sigma*std, sigma = (y==1 ? +1 : -1),
//       a = logit0+eps, b = logit1+eps.
// Each thread owns 2 consecutive rows -> all global loads are 8-16B/lane.
__global__ __launch_bounds__(256) void bcc_partial(
    const float4* __restrict__ logit4,   // [npair]
    const float2* __restrict__ var2,     // [npair]
    const int2*   __restrict__ true2,    // [npair]
    const float4* __restrict__ noise4,   // [TSAMP][npair]
    float* __restrict__ partial,         // [32][nblk]
    int npair, int nblk)
{
    float acc[TSAMP];
    #pragma unroll
    for (int t = 0; t < TSAMP; ++t) acc[t] = 0.0f;
    float u_acc = 0.0f, vd_acc = 0.0f;

    const int stride = gridDim.x * blockDim.x;
    for (int p = blockIdx.x * blockDim.x + threadIdx.x; p < npair; p += stride) {
        const float4 lg = logit4[p];
        const float2 v  = var2[p];
        const int2   yy = true2[p];

        // row 0
        const float sg0 = yy.x ? 1.0f : -1.0f;
        const float d0  = sg0 * (lg.x - lg.y);          // sigma*(a-b); eps cancels
        const float ss0 = sg0 * (__fsqrt_rn(v.x) + FEPS);
        // row 1
        const float sg1 = yy.y ? 1.0f : -1.0f;
        const float d1  = sg1 * (lg.z - lg.w);
        const float ss1 = sg1 * (__fsqrt_rn(v.y) + FEPS);

        vd_acc += (__expf(v.x) - 1.0f) + (__expf(v.y) - 1.0f);
        u_acc  -= softplus(d0) + softplus(d1);

        const float4* nptr = noise4 + p;
        #pragma unroll
        for (int t = 0; t < TSAMP; ++t) {
            const float4 nz = nptr[(size_t)t * (size_t)npair];
            const float x0 = fmaf(ss0, nz.x - nz.y, d0);
            const float x1 = fmaf(ss1, nz.z - nz.w, d1);
            acc[t] -= softplus(x0) + softplus(x1);
        }
    }

    // block reduction of the 32 accumulators (deterministic, no atomics)
    __shared__ float s_part[4][32];
    const int lane = threadIdx.x & 63;
    const int wav  = threadIdx.x >> 6;
    #pragma unroll
    for (int a = 0; a < 32; ++a) {
        float vv = (a < TSAMP) ? acc[a] : ((a == TSAMP) ? u_acc : vd_acc);
        #pragma unroll
        for (int off = 32; off >= 1; off >>= 1)
            vv += __shfl_down(vv, off, 64);
        if (lane == 0) s_part[wav][a] = vv;
    }
    __syncthreads();
    if (threadIdx.x < 32) {
        const int a = threadIdx.x;
        const float s = s_part[0][a] + s_part[1][a] + s_part[2][a] + s_part[3][a];
        partial[(size_t)a * (size_t)nblk + blockIdx.x] = s;
    }
}

// Kernel 2: 32 blocks, block a reduces partial[a][0..nblk) -> res32[a].
__global__ __launch_bounds__(256) void bcc_reduce(
    const float* __restrict__ partial,   // [32][nblk]
    int nblk, float* __restrict__ res32) // [32]
{
    const int a = blockIdx.x;
    float s = 0.0f;
    for (int j = threadIdx.x; j < nblk; j += 256)
        s += partial[(size_t)a * (size_t)nblk + j];
    #pragma unroll
    for (int off = 32; off >= 1; off >>= 1)
        s += __shfl_down(s, off, 64);
    __shared__ float sw[4];
    if ((threadIdx.x & 63) == 0) sw[threadIdx.x >> 6] = s;
    __syncthreads();
    if (threadIdx.x == 0)
        res32[a] = sw[0] + sw[1] + sw[2] + sw[3];
}

// Kernel 3: scalar epilogue on the 32 reduced sums.
__global__ __launch_bounds__(64) void bcc_epilogue(
    const float* __restrict__ res32, float invN, float* __restrict__ out)
{
    if (threadIdx.x == 0) {
        const float U  = -res32[30] * invN;          // undistorted_loss
        const float vd =  res32[31] * invN;          // mean variance_depressor
        float mc_sum = 0.0f;
        #pragma unroll
        for (int t = 0; t < TSAMP; ++t) {
            const float D = -res32[t] * invN;        // distorted_loss[t]
            const float x = U - D;
            const float e = (x > 0.0f) ? x : expm1f(x);   // elu(x)
            mc_sum += -e;                             // monte_carlo[t]
        }
        const float variance_loss = (mc_sum / (float)TSAMP) * U;
        out[0] = variance_loss + U + vd;
    }
}

extern "C" void kernel_launch(void* const* d_in, const int* in_sizes, int n_in,
                              void* d_out, int out_size, void* d_ws, size_t ws_size,
                              hipStream_t stream) {
    const float* logit = (const float*)d_in[0];   // [N,2] f32
    const float* var   = (const float*)d_in[1];   // [N,1] f32
    const int*   tru   = (const int*)d_in[2];     // [N]   i32
    const float* noise = (const float*)d_in[3];   // [30,N,2] f32
    float* out = (float*)d_out;

    const int N = in_sizes[1];          // var has N elements
    const int npair = N / 2;

    int nblk = 2048;
    const size_t need = (size_t)32 * (size_t)nblk * sizeof(float) + 32 * sizeof(float);
    if (ws_size < need) {
        nblk = (int)((ws_size - 32 * sizeof(float)) / (32 * sizeof(float)));
        if (nblk < 1) nblk = 1;
    }
    float* partial = (float*)d_ws;                       // [32][nblk]
    float* res32   = partial + (size_t)32 * (size_t)nblk; // [32]

    bcc_partial<<<nblk, 256, 0, stream>>>(
        (const float4*)logit, (const float2*)var, (const int2*)tru,
        (const float4*)noise, partial, npair, nblk);

    bcc_reduce<<<32, 256, 0, stream>>>(partial, nblk, res32);

    bcc_epilogue<<<1, 64, 0, stream>>>(res32, 1.0f / (float)N, out);
}

// Round 3
// 65.582 us; speedup vs baseline: 2.2469x; 1.0426x over previous
//
#include <hip/hip_runtime.h>
#include <math.h>

#define TSAMP 30
#define NGRP  5          // t-groups
#define TPG   6          // t's per group (NGRP*TPG == TSAMP)
#define FEPS  1e-15f

// softplus(x) = log1p(exp(x)), stable, 1 exp + 1 log
__device__ __forceinline__ float softplus(float x) {
    return fmaxf(x, 0.0f) + __logf(1.0f + __expf(-fabsf(x)));
}

// Kernel 1: grid = (NGRP * pblk) blocks. g = bid % NGRP owns t in [g*TPG, g*TPG+TPG).
// Adjacent blocks are different groups on the same p-range -> logit/var/true
// re-reads hit L2/L3, noise is read exactly once chip-wide.
//   acc[k]  = sum_i -softplus(d_i + ss_i*(n0-n1))   (t = g*TPG+k)
//   g==0 additionally: u = sum_i -softplus(d_i),  vd = sum_i (exp(var_i)-1)
// Each thread owns 2 rows (one pair) per iteration -> 16B/lane noise loads.
__global__ __launch_bounds__(256) void bcc_partial(
    const float4* __restrict__ logit4,   // [npair]
    const float2* __restrict__ var2,     // [npair]
    const int2*   __restrict__ true2,    // [npair]
    const float4* __restrict__ noise4,   // [TSAMP][npair]
    float* __restrict__ partial,         // [32][pblk]
    int npair, int pblk)
{
    const int g     = blockIdx.x % NGRP;
    const int pb    = blockIdx.x / NGRP;
    const int tbase = g * TPG;

    float acc[TPG];
    #pragma unroll
    for (int k = 0; k < TPG; ++k) acc[k] = 0.0f;
    float u_acc = 0.0f, vd_acc = 0.0f;

    const int pstride = pblk * 256;
    const float4* nbase = noise4 + (size_t)tbase * (size_t)npair;

    for (int p = pb * 256 + threadIdx.x; p < npair; p += pstride) {
        const float4 lg = logit4[p];
        const float2 v  = var2[p];
        const int2   yy = true2[p];

        const float sg0 = yy.x ? 1.0f : -1.0f;
        const float d0  = sg0 * (lg.x - lg.y);
        const float ss0 = sg0 * (__fsqrt_rn(v.x) + FEPS);
        const float sg1 = yy.y ? 1.0f : -1.0f;
        const float d1  = sg1 * (lg.z - lg.w);
        const float ss1 = sg1 * (__fsqrt_rn(v.y) + FEPS);

        if (g == 0) {
            vd_acc += (__expf(v.x) - 1.0f) + (__expf(v.y) - 1.0f);
            u_acc  -= softplus(d0) + softplus(d1);
        }

        const float4* nptr = nbase + p;
        #pragma unroll
        for (int k = 0; k < TPG; ++k) {
            const float4 nz = nptr[(size_t)k * (size_t)npair];
            const float x0 = fmaf(ss0, nz.x - nz.y, d0);
            const float x1 = fmaf(ss1, nz.z - nz.w, d1);
            acc[k] -= softplus(x0) + softplus(x1);
        }
    }

    // block-reduce TPG+2 slots (deterministic)
    __shared__ float s_part[4][TPG + 2];
    const int lane = threadIdx.x & 63;
    const int wav  = threadIdx.x >> 6;
    #pragma unroll
    for (int a = 0; a < TPG + 2; ++a) {
        float vv = (a < TPG) ? acc[a] : ((a == TPG) ? u_acc : vd_acc);
        #pragma unroll
        for (int off = 32; off >= 1; off >>= 1)
            vv += __shfl_down(vv, off, 64);
        if (lane == 0) s_part[wav][a] = vv;
    }
    __syncthreads();
    if (threadIdx.x < TPG + 2) {
        const int a = threadIdx.x;
        const float s = s_part[0][a] + s_part[1][a] + s_part[2][a] + s_part[3][a];
        if (a < TPG)
            partial[(size_t)(tbase + a) * (size_t)pblk + pb] = s;
        else if (g == 0)
            partial[(size_t)(TSAMP + (a - TPG)) * (size_t)pblk + pb] = s;
    }
}

// Kernel 2: 32 blocks, block a reduces partial[a][0..pblk) -> res32[a].
__global__ __launch_bounds__(256) void bcc_reduce(
    const float* __restrict__ partial,   // [32][pblk]
    int pblk, float* __restrict__ res32) // [32]
{
    const int a = blockIdx.x;
    float s = 0.0f;
    for (int j = threadIdx.x; j < pblk; j += 256)
        s += partial[(size_t)a * (size_t)pblk + j];
    #pragma unroll
    for (int off = 32; off >= 1; off >>= 1)
        s += __shfl_down(s, off, 64);
    __shared__ float sw[4];
    if ((threadIdx.x & 63) == 0) sw[threadIdx.x >> 6] = s;
    __syncthreads();
    if (threadIdx.x == 0)
        res32[a] = sw[0] + sw[1] + sw[2] + sw[3];
}

// Kernel 3: scalar epilogue on the 32 reduced sums.
__global__ __launch_bounds__(64) void bcc_epilogue(
    const float* __restrict__ res32, float invN, float* __restrict__ out)
{
    if (threadIdx.x == 0) {
        const float U  = -res32[30] * invN;          // undistorted_loss
        const float vd =  res32[31] * invN;          // mean variance_depressor
        float mc_sum = 0.0f;
        #pragma unroll
        for (int t = 0; t < TSAMP; ++t) {
            const float D = -res32[t] * invN;        // distorted_loss[t]
            const float x = U - D;
            const float e = (x > 0.0f) ? x : expm1f(x);   // elu(x)
            mc_sum += -e;                             // monte_carlo[t]
        }
        const float variance_loss = (mc_sum / (float)TSAMP) * U;
        out[0] = variance_loss + U + vd;
    }
}

extern "C" void kernel_launch(void* const* d_in, const int* in_sizes, int n_in,
                              void* d_out, int out_size, void* d_ws, size_t ws_size,
                              hipStream_t stream) {
    const float* logit = (const float*)d_in[0];   // [N,2] f32
    const float* var   = (const float*)d_in[1];   // [N,1] f32
    const int*   tru   = (const int*)d_in[2];     // [N]   i32
    const float* noise = (const float*)d_in[3];   // [30,N,2] f32
    float* out = (float*)d_out;

    const int N = in_sizes[1];          // var has N elements
    const int npair = N / 2;

    int pblk = 1024;                    // 2 grid-stride iterations per thread
    {
        int maxp = (npair + 255) / 256;
        if (pblk > maxp) pblk = maxp;
        const size_t need = (size_t)32 * (size_t)pblk * sizeof(float) + 32 * sizeof(float);
        if (ws_size < need) {
            pblk = (int)((ws_size - 32 * sizeof(float)) / (32 * sizeof(float)));
            if (pblk < 1) pblk = 1;
        }
    }
    float* partial = (float*)d_ws;                        // [32][pblk]
    float* res32   = partial + (size_t)32 * (size_t)pblk; // [32]

    bcc_partial<<<NGRP * pblk, 256, 0, stream>>>(
        (const float4*)logit, (const float2*)var, (const int2*)tru,
        (const float4*)noise, partial, npair, pblk);

    bcc_reduce<<<32, 256, 0, stream>>>(partial, pblk, res32);

    bcc_epilogue<<<1, 64, 0, stream>>>(res32, 1.0f / (float)N, out);
}